// Round 7
// baseline (532.460 us; speedup 1.0000x reference)
//
#include <hip/hip_runtime.h>
#include <hip/hip_bf16.h>

// SimpleMoE: B=2,S=2048 -> 4096 tokens, DIM=1024, FF=4096, E=8, top-2 routing.
// Round 7: round-6 structure with the bf16x2 packing done via f2bf (bit_cast
// of __hip_bfloat162 doesn't compile). No weight-transpose kernels; GEMMs
// stage B directly from native fp32 weights (reg-staged global_load_dwordx4
// -> pack -> swizzled padded LDS [128][40]); A staged via gload_lds with
// pre-swizzled source chunks. Counted vmcnt(2) keeps B loads in flight.

typedef __attribute__((ext_vector_type(8))) short bf16x8;
typedef __attribute__((ext_vector_type(4))) float f32x4;

__device__ __forceinline__ unsigned short f2bf(float f) {
  unsigned u = __builtin_bit_cast(unsigned, f);
  u += 0x7FFFu + ((u >> 16) & 1u);
  return (unsigned short)(u >> 16);
}

__device__ __forceinline__ unsigned pk2bf(float lo, float hi) {
  return ((unsigned)f2bf(hi) << 16) | (unsigned)f2bf(lo);
}

__device__ __forceinline__ void gload_lds16(const void* g, void* l) {
  __builtin_amdgcn_global_load_lds(
      (const __attribute__((address_space(1))) unsigned int*)g,
      (__attribute__((address_space(3))) unsigned int*)l, 16, 0, 0);
}

// inline-asm LDS read: keeps the compiler from serializing ds_read behind
// in-flight global_load_lds (false alias) with a vmcnt(0).
__device__ __forceinline__ bf16x8 ldsr128(const void* p) {
  bf16x8 r;
  unsigned a = (unsigned)(unsigned long long)p;
  asm volatile("ds_read_b128 %0, %1" : "=v"(r) : "v"(a));
  return r;
}

// inline-asm global fp32x4 load: issue early, wait with counted vmcnt later.
__device__ __forceinline__ f32x4 gload4(const float* p) {
  f32x4 r;
  asm volatile("global_load_dwordx4 %0, %1, off" : "=v"(r) : "v"(p) : "memory");
  return r;
}

// ---------------- gate: logits (fp64), softmax, top-2, counts ----------------
__global__ __launch_bounds__(256) void gate_kernel(
    const float* __restrict__ x, const float* __restrict__ Wg,
    const float* __restrict__ bg, int* __restrict__ tok_e,
    float* __restrict__ tok_w, int* __restrict__ counts) {
  const int wave = threadIdx.x >> 6;
  const int lane = threadIdx.x & 63;
  const int t = blockIdx.x * 4 + wave;
  const float* xr = x + (size_t)t * 1024;
  double acc[8] = {0, 0, 0, 0, 0, 0, 0, 0};
  for (int i = 0; i < 16; ++i) {
    const int d = i * 64 + lane;
    const double xv = (double)xr[d];
    const float* wr = Wg + d * 8;
#pragma unroll
    for (int e = 0; e < 8; ++e) acc[e] += xv * (double)wr[e];
  }
#pragma unroll
  for (int e = 0; e < 8; ++e) {
    double v = acc[e];
#pragma unroll
    for (int off = 32; off > 0; off >>= 1) v += __shfl_xor(v, off, 64);
    acc[e] = v + (double)bg[e];
  }
  if (lane == 0) {
    int e0 = 0;
#pragma unroll
    for (int e = 1; e < 8; ++e)
      if (acc[e] > acc[e0]) e0 = e;
    int e1 = (e0 == 0) ? 1 : 0;
#pragma unroll
    for (int e = 0; e < 8; ++e) {
      if (e != e0 && acc[e] > acc[e1]) e1 = e;
    }
    const double m = acc[e0];
    double s = 0.0;
#pragma unroll
    for (int e = 0; e < 8; ++e) s += exp(acc[e] - m);
    const double p0 = exp(acc[e0] - m) / s;
    const double p1 = exp(acc[e1] - m) / s;
    const double den = p0 + p1 + 1e-9;
    tok_e[2 * t] = e0;
    tok_e[2 * t + 1] = e1;
    tok_w[2 * t] = (float)(p0 / den);
    tok_w[2 * t + 1] = (float)(p1 / den);
    atomicAdd(&counts[e0], 1);
    atomicAdd(&counts[e1], 1);
  }
}

__global__ void scan_kernel(const int* __restrict__ counts,
                            int* __restrict__ offsets,
                            int* __restrict__ cursors) {
  if (threadIdx.x == 0) {
    int s = 0;
    for (int e = 0; e < 8; ++e) {
      offsets[e] = s;
      cursors[e] = s;
      s += counts[e];
    }
  }
}

__global__ __launch_bounds__(256) void scatter_kernel(
    const int* __restrict__ tok_e, int* __restrict__ cursors,
    int* __restrict__ pair_token, int* __restrict__ tok_slot) {
  const int t = blockIdx.x * 256 + threadIdx.x;
  if (t >= 4096) return;
#pragma unroll
  for (int j = 0; j < 2; ++j) {
    const int e = tok_e[2 * t + j];
    const int slot = atomicAdd(&cursors[e], 1);
    pair_token[slot] = t;
    tok_slot[2 * t + j] = slot;
  }
}

// ---------------- x -> bf16 ----------------
__global__ __launch_bounds__(256) void xconv_kernel(
    const float* __restrict__ x, unsigned short* __restrict__ xb) {
  const size_t i = ((size_t)blockIdx.x * 256 + threadIdx.x) * 4;
  const float4 v = *(const float4*)(x + i);
  ushort4 pk;
  pk.x = f2bf(v.x); pk.y = f2bf(v.y); pk.z = f2bf(v.z); pk.w = f2bf(v.w);
  *(ushort4*)(xb + i) = pk;
}

// ---------------- GEMM1: H[slot][n] = relu(xb[tok] @ W1[e] + b1) ------------
// B read directly from W1[e][k][f] fp32, transposed+converted into LDS.
__global__ __launch_bounds__(256) void gemm1_kernel(
    const unsigned short* __restrict__ xb, const float* __restrict__ W1,
    const float* __restrict__ b1, const int* __restrict__ counts,
    const int* __restrict__ offsets, const int* __restrict__ pair_token,
    unsigned short* __restrict__ H, int FC, int f0) {
  const int bid = blockIdx.x;
  const int e = bid & 7;           // XCD pinning
  const int lid = bid >> 3;
  const int m0 = (lid & 31) * 128; // m fastest: B panel reused by m-group
  const int n0 = (lid >> 5) * 128;
  const int count = counts[e];
  if (m0 >= count) return;
  const int offset = offsets[e];

  __shared__ __align__(16) unsigned short Alds[2][128 * 32];
  __shared__ __align__(16) unsigned short Blds[2][128 * 40];
  __shared__ int toklds[128];

  const int tid = threadIdx.x;
  if (tid < 128) {
    int r = m0 + tid;
    if (r >= count) r = count - 1;
    toklds[tid] = pair_token[offset + r];
  }
  __syncthreads();

  const int lane = tid & 63;
  const int wave = tid >> 6;

  // A staging: gload_lds, source chunk pre-swizzled (xr = (row>>1)&3)
  const int srow = lane >> 2;
  const int kc = lane & 3;
  const unsigned short* aga[2];
  int ldso[2];
#pragma unroll
  for (int i = 0; i < 2; ++i) {
    const int ar = wave * 32 + i * 16 + srow;
    const int xr = (ar >> 1) & 3;
    aga[i] = xb + (size_t)toklds[ar] * 1024 + (kc ^ xr) * 8;
    ldso[i] = (wave * 32 + i * 16) * 32;
  }

  // B staging: thread owns a 4k x 4f block
  const int fq = tid & 31;        // f quad: f_local = fq*4+j
  const int kb = (tid >> 5) * 4;  // k base within 32-step
  const float* bsrc =
      W1 + ((size_t)e << 22) + (size_t)kb * 4096 + (f0 + n0 + fq * 4);
  int wrB[4];
#pragma unroll
  for (int j = 0; j < 4; ++j)
    wrB[j] = (fq * 4 + j) * 40 + (kb ^ (((fq >> 1) & 3) << 3));

  // fragment read offsets (shorts)
  const int wm = (wave >> 1) * 64;
  const int wn = (wave & 1) * 64;
  const int l16 = lane & 15;
  const int lk = lane >> 4;
  int rdA[4], rdB[4];
#pragma unroll
  for (int mi = 0; mi < 4; ++mi) {
    const int row = wm + mi * 16 + l16;
    rdA[mi] = row * 32 + ((lk ^ ((row >> 1) & 3)) << 3);
  }
#pragma unroll
  for (int nj = 0; nj < 4; ++nj) {
    const int f = wn + nj * 16 + l16;
    rdB[nj] = f * 40 + ((lk ^ ((f >> 3) & 3)) << 3);
  }

  f32x4 acc[4][4] = {};
  f32x4 bq0, bq1, bq2, bq3;

  auto BLOAD = [&](int kt) {
    const float* p = bsrc + (size_t)kt * 4096;
    bq0 = gload4(p);
    bq1 = gload4(p + 4096);
    bq2 = gload4(p + 8192);
    bq3 = gload4(p + 12288);
  };
  auto STAGE_A = [&](int kt, int buf) {
#pragma unroll
    for (int i = 0; i < 2; ++i)
      gload_lds16(aga[i] + kt, &Alds[buf][ldso[i]]);
  };
  auto BWRITE = [&](int buf) {
    asm volatile("s_waitcnt vmcnt(2)" ::: "memory");  // B loads done, A in flight
    __builtin_amdgcn_sched_barrier(0);
#pragma unroll
    for (int j = 0; j < 4; ++j) {
      uint2 pk;
      pk.x = pk2bf(bq0[j], bq1[j]);
      pk.y = pk2bf(bq2[j], bq3[j]);
      *(uint2*)&Blds[buf][wrB[j]] = pk;
    }
  };
  auto COMPUTE = [&](int buf) {
    bf16x8 af[4], bfr[4];
#pragma unroll
    for (int mi = 0; mi < 4; ++mi) af[mi] = ldsr128(&Alds[buf][rdA[mi]]);
#pragma unroll
    for (int nj = 0; nj < 4; ++nj) bfr[nj] = ldsr128(&Blds[buf][rdB[nj]]);
    asm volatile("s_waitcnt lgkmcnt(0)" ::: "memory");
    __builtin_amdgcn_sched_barrier(0);
#pragma unroll
    for (int mi = 0; mi < 4; ++mi)
#pragma unroll
      for (int nj = 0; nj < 4; ++nj)
        acc[mi][nj] = __builtin_amdgcn_mfma_f32_16x16x32_bf16(
            af[mi], bfr[nj], acc[mi][nj], 0, 0, 0);
  };

  BLOAD(0);
  STAGE_A(0, 0);
  BWRITE(0);
  __syncthreads();
  int cur = 0;
  for (int t = 0; t < 31; ++t) {
    BLOAD((t + 1) * 32);          // issue next B loads (overlap compute)
    STAGE_A((t + 1) * 32, cur ^ 1);
    COMPUTE(cur);
    BWRITE(cur ^ 1);              // counted wait + convert + ds_write
    __syncthreads();
    cur ^= 1;
  }
  COMPUTE(cur);

#pragma unroll
  for (int mi = 0; mi < 4; ++mi) {
#pragma unroll
    for (int r = 0; r < 4; ++r) {
      const int rl = m0 + wm + mi * 16 + lk * 4 + r;
      if (rl >= count) continue;
      unsigned short* hrow = H + (size_t)(offset + rl) * FC;
#pragma unroll
      for (int nj = 0; nj < 4; ++nj) {
        const int c = n0 + wn + nj * 16 + l16;
        float v = acc[mi][nj][r] + b1[e * 4096 + f0 + c];
        hrow[c] = f2bf(v > 0.f ? v : 0.f);
      }
    }
  }
}

// ------- GEMM2: P[slot][d] (+)= H[slot] @ W2[e] (+ b2) ----------------------
// B read directly from W2[e][f][d] fp32.
__global__ __launch_bounds__(256) void gemm2_kernel(
    const unsigned short* __restrict__ H, const float* __restrict__ W2,
    const float* __restrict__ b2, const int* __restrict__ counts,
    const int* __restrict__ offsets, float* __restrict__ P, int FC, int f0,
    int firstChunk) {
  const int bid = blockIdx.x;
  const int e = bid & 7;
  const int lid = bid >> 3;
  const int m0 = (lid & 31) * 128;
  const int n0 = (lid >> 5) * 128;  // 8 n-tiles (N=1024)
  const int count = counts[e];
  if (m0 >= count) return;
  const int offset = offsets[e];

  __shared__ __align__(16) unsigned short Alds[2][128 * 32];
  __shared__ __align__(16) unsigned short Blds[2][128 * 40];

  const int tid = threadIdx.x;
  const int lane = tid & 63;
  const int wave = tid >> 6;

  const int srow = lane >> 2;
  const int kc = lane & 3;
  const unsigned short* aga[2];
  int ldso[2];
#pragma unroll
  for (int i = 0; i < 2; ++i) {
    const int tr = wave * 32 + i * 16 + srow;  // tile row
    int ar = m0 + tr;
    if (ar >= count) ar = count - 1;
    const int xr = (tr >> 1) & 3;
    aga[i] = H + (size_t)(offset + ar) * FC + (kc ^ xr) * 8;
    ldso[i] = (wave * 32 + i * 16) * 32;
  }

  const int fq = tid & 31;
  const int kb = (tid >> 5) * 4;
  const float* bsrc =
      W2 + ((size_t)e << 22) + (size_t)(f0 + kb) * 1024 + (n0 + fq * 4);
  int wrB[4];
#pragma unroll
  for (int j = 0; j < 4; ++j)
    wrB[j] = (fq * 4 + j) * 40 + (kb ^ (((fq >> 1) & 3) << 3));

  const int wm = (wave >> 1) * 64;
  const int wn = (wave & 1) * 64;
  const int l16 = lane & 15;
  const int lk = lane >> 4;
  int rdA[4], rdB[4];
#pragma unroll
  for (int mi = 0; mi < 4; ++mi) {
    const int row = wm + mi * 16 + l16;
    rdA[mi] = row * 32 + ((lk ^ ((row >> 1) & 3)) << 3);
  }
#pragma unroll
  for (int nj = 0; nj < 4; ++nj) {
    const int f = wn + nj * 16 + l16;
    rdB[nj] = f * 40 + ((lk ^ ((f >> 3) & 3)) << 3);
  }

  f32x4 acc[4][4] = {};
  f32x4 bq0, bq1, bq2, bq3;

  auto BLOAD = [&](int kt) {
    const float* p = bsrc + (size_t)kt * 1024;
    bq0 = gload4(p);
    bq1 = gload4(p + 1024);
    bq2 = gload4(p + 2048);
    bq3 = gload4(p + 3072);
  };
  auto STAGE_A = [&](int kt, int buf) {
#pragma unroll
    for (int i = 0; i < 2; ++i)
      gload_lds16(aga[i] + kt, &Alds[buf][ldso[i]]);
  };
  auto BWRITE = [&](int buf) {
    asm volatile("s_waitcnt vmcnt(2)" ::: "memory");
    __builtin_amdgcn_sched_barrier(0);
#pragma unroll
    for (int j = 0; j < 4; ++j) {
      uint2 pk;
      pk.x = pk2bf(bq0[j], bq1[j]);
      pk.y = pk2bf(bq2[j], bq3[j]);
      *(uint2*)&Blds[buf][wrB[j]] = pk;
    }
  };
  auto COMPUTE = [&](int buf) {
    bf16x8 af[4], bfr[4];
#pragma unroll
    for (int mi = 0; mi < 4; ++mi) af[mi] = ldsr128(&Alds[buf][rdA[mi]]);
#pragma unroll
    for (int nj = 0; nj < 4; ++nj) bfr[nj] = ldsr128(&Blds[buf][rdB[nj]]);
    asm volatile("s_waitcnt lgkmcnt(0)" ::: "memory");
    __builtin_amdgcn_sched_barrier(0);
#pragma unroll
    for (int mi = 0; mi < 4; ++mi)
#pragma unroll
      for (int nj = 0; nj < 4; ++nj)
        acc[mi][nj] = __builtin_amdgcn_mfma_f32_16x16x32_bf16(
            af[mi], bfr[nj], acc[mi][nj], 0, 0, 0);
  };

  const int NTk = FC / 32;
  BLOAD(0);
  STAGE_A(0, 0);
  BWRITE(0);
  __syncthreads();
  int cur = 0;
  for (int t = 0; t < NTk - 1; ++t) {
    BLOAD((t + 1) * 32);
    STAGE_A((t + 1) * 32, cur ^ 1);
    COMPUTE(cur);
    BWRITE(cur ^ 1);
    __syncthreads();
    cur ^= 1;
  }
  COMPUTE(cur);

#pragma unroll
  for (int mi = 0; mi < 4; ++mi) {
#pragma unroll
    for (int r = 0; r < 4; ++r) {
      const int rl = m0 + wm + mi * 16 + lk * 4 + r;
      if (rl >= count) continue;
      float* prow = P + (size_t)(offset + rl) * 1024;
#pragma unroll
      for (int nj = 0; nj < 4; ++nj) {
        const int c = n0 + wn + nj * 16 + l16;
        float v = acc[mi][nj][r];
        if (firstChunk) {
          prow[c] = v + b2[e * 1024 + c];
        } else {
          prow[c] += v;
        }
      }
    }
  }
}

// ---------------- combine: out[t] = w0*P[s0] + w1*P[s1] ----------------
__global__ __launch_bounds__(256) void combine_kernel(
    const float* __restrict__ P, const int* __restrict__ tok_slot,
    const float* __restrict__ tok_w, float* __restrict__ out) {
  const int t = blockIdx.x;
  const int d = threadIdx.x * 4;
  const int s0 = tok_slot[2 * t];
  const int s1 = tok_slot[2 * t + 1];
  const float w0 = tok_w[2 * t];
  const float w1 = tok_w[2 * t + 1];
  const float4 a = *(const float4*)&P[(size_t)s0 * 1024 + d];
  const float4 b = *(const float4*)&P[(size_t)s1 * 1024 + d];
  float4 r;
  r.x = w0 * a.x + w1 * b.x;
  r.y = w0 * a.y + w1 * b.y;
  r.z = w0 * a.z + w1 * b.z;
  r.w = w0 * a.w + w1 * b.w;
  *(float4*)&out[(size_t)t * 1024 + d] = r;
}

extern "C" void kernel_launch(void* const* d_in, const int* in_sizes, int n_in,
                              void* d_out, int out_size, void* d_ws,
                              size_t ws_size, hipStream_t stream) {
  const float* x = (const float*)d_in[0];
  const float* Wg = (const float*)d_in[1];
  const float* bg = (const float*)d_in[2];
  const float* W1 = (const float*)d_in[3];
  const float* b1 = (const float*)d_in[4];
  const float* W2 = (const float*)d_in[5];
  const float* b2 = (const float*)d_in[6];
  float* out = (float*)d_out;

  char* w = (char*)d_ws;
  int* counts = (int*)w;
  int* offsets = counts + 16;
  int* cursors = counts + 32;
  int* tok_e = (int*)(w + 1024);
  float* tok_w = (float*)(w + 1024 + 32768);
  int* pair_token = (int*)(w + 1024 + 65536);
  int* tok_slot = (int*)(w + 1024 + 98304);
  unsigned short* xb = (unsigned short*)(w + 256 * 1024);  // 8MB
  float* P = (float*)(w + 256 * 1024 + 8 * 1024 * 1024);   // 32MB
  unsigned short* Hc =
      (unsigned short*)(w + 256 * 1024 + 8 * 1024 * 1024 + 32 * 1024 * 1024);
  const size_t avail =
      ws_size - (256 * 1024 + 8 * 1024 * 1024 + 32 * 1024 * 1024);

  // H chunk: 8192 * FC * 2 bytes
  int FC = 4096;
  while (FC > 256 && (size_t)8192 * FC * 2 > avail) FC >>= 1;

  (void)hipMemsetAsync(counts, 0, 64, stream);

  gate_kernel<<<1024, 256, 0, stream>>>(x, Wg, bg, tok_e, tok_w, counts);
  scan_kernel<<<1, 64, 0, stream>>>(counts, offsets, cursors);
  scatter_kernel<<<16, 256, 0, stream>>>(tok_e, cursors, pair_token, tok_slot);
  xconv_kernel<<<4096, 256, 0, stream>>>(x, xb);

  const int NT = FC / 128;
  for (int f0 = 0; f0 < 4096; f0 += FC) {
    gemm1_kernel<<<8 * 32 * NT, 256, 0, stream>>>(
        xb, W1, b1, counts, offsets, pair_token, Hc, FC, f0);
    gemm2_kernel<<<8 * 32 * 8, 256, 0, stream>>>(
        Hc, W2, b2, counts, offsets, P, FC, f0, f0 == 0 ? 1 : 0);
  }
  combine_kernel<<<4096, 256, 0, stream>>>(P, tok_slot, tok_w, out);
}

// Round 8
// 473.121 us; speedup vs baseline: 1.1254x; 1.1254x over previous
//
#include <hip/hip_runtime.h>
#include <hip/hip_bf16.h>

// SimpleMoE: B=2,S=2048 -> 4096 tokens, DIM=1024, FF=4096, E=8, top-2 routing.
// Round 8: revert to round-5 bf16 pre-transposed weights + gload_lds GEMMs;
// add (1) counted-vmcnt 2-barrier pipeline (no full drain per k-step),
// (2) XOR source-chunk swizzle on A and B staging (+ matching read XOR)
// to cut the 8-way ds_read_b128 bank conflict to 2-way (free).

typedef __attribute__((ext_vector_type(8))) short bf16x8;
typedef __attribute__((ext_vector_type(4))) float f32x4;

__device__ __forceinline__ unsigned short f2bf(float f) {
  unsigned u = __builtin_bit_cast(unsigned, f);
  u += 0x7FFFu + ((u >> 16) & 1u);
  return (unsigned short)(u >> 16);
}

__device__ __forceinline__ void gload_lds16(const void* g, void* l) {
  __builtin_amdgcn_global_load_lds(
      (const __attribute__((address_space(1))) unsigned int*)g,
      (__attribute__((address_space(3))) unsigned int*)l, 16, 0, 0);
}

// inline-asm LDS read: keeps the compiler from serializing ds_read behind
// in-flight global_load_lds (false alias) with a vmcnt(0).
__device__ __forceinline__ bf16x8 ldsr128(const void* p) {
  bf16x8 r;
  unsigned a = (unsigned)(unsigned long long)p;
  asm volatile("ds_read_b128 %0, %1" : "=v"(r) : "v"(a));
  return r;
}

// ---------------- gate: logits (fp64), softmax, top-2, counts ----------------
__global__ __launch_bounds__(256) void gate_kernel(
    const float* __restrict__ x, const float* __restrict__ Wg,
    const float* __restrict__ bg, int* __restrict__ tok_e,
    float* __restrict__ tok_w, int* __restrict__ counts) {
  const int wave = threadIdx.x >> 6;
  const int lane = threadIdx.x & 63;
  const int t = blockIdx.x * 4 + wave;
  const float* xr = x + (size_t)t * 1024;
  double acc[8] = {0, 0, 0, 0, 0, 0, 0, 0};
  for (int i = 0; i < 16; ++i) {
    const int d = i * 64 + lane;
    const double xv = (double)xr[d];
    const float* wr = Wg + d * 8;
#pragma unroll
    for (int e = 0; e < 8; ++e) acc[e] += xv * (double)wr[e];
  }
#pragma unroll
  for (int e = 0; e < 8; ++e) {
    double v = acc[e];
#pragma unroll
    for (int off = 32; off > 0; off >>= 1) v += __shfl_xor(v, off, 64);
    acc[e] = v + (double)bg[e];
  }
  if (lane == 0) {
    int e0 = 0;
#pragma unroll
    for (int e = 1; e < 8; ++e)
      if (acc[e] > acc[e0]) e0 = e;
    int e1 = (e0 == 0) ? 1 : 0;
#pragma unroll
    for (int e = 0; e < 8; ++e) {
      if (e != e0 && acc[e] > acc[e1]) e1 = e;
    }
    const double m = acc[e0];
    double s = 0.0;
#pragma unroll
    for (int e = 0; e < 8; ++e) s += exp(acc[e] - m);
    const double p0 = exp(acc[e0] - m) / s;
    const double p1 = exp(acc[e1] - m) / s;
    const double den = p0 + p1 + 1e-9;
    tok_e[2 * t] = e0;
    tok_e[2 * t + 1] = e1;
    tok_w[2 * t] = (float)(p0 / den);
    tok_w[2 * t + 1] = (float)(p1 / den);
    atomicAdd(&counts[e0], 1);
    atomicAdd(&counts[e1], 1);
  }
}

// ---------------- scan + scatter fused (single block) ----------------
__global__ __launch_bounds__(256) void scan_scatter_kernel(
    const int* __restrict__ counts, const int* __restrict__ tok_e,
    int* __restrict__ offsets, int* __restrict__ pair_token,
    int* __restrict__ tok_slot) {
  __shared__ int scur[8];
  const int tid = threadIdx.x;
  if (tid == 0) {
    int s = 0;
    for (int e = 0; e < 8; ++e) {
      offsets[e] = s;
      scur[e] = s;
      s += counts[e];
    }
  }
  __syncthreads();
  for (int t = tid; t < 4096; t += 256) {
#pragma unroll
    for (int j = 0; j < 2; ++j) {
      const int e = tok_e[2 * t + j];
      const int slot = atomicAdd(&scur[e], 1);
      pair_token[slot] = t;
      tok_slot[2 * t + j] = slot;
    }
  }
}

// ---------------- x -> bf16 ----------------
__global__ __launch_bounds__(256) void xconv_kernel(
    const float* __restrict__ x, unsigned short* __restrict__ xb) {
  const size_t i = ((size_t)blockIdx.x * 256 + threadIdx.x) * 4;
  const float4 v = *(const float4*)(x + i);
  ushort4 pk;
  pk.x = f2bf(v.x); pk.y = f2bf(v.y); pk.z = f2bf(v.z); pk.w = f2bf(v.w);
  *(ushort4*)(xb + i) = pk;
}

// ---------------- W1[e][k][f] -> W1t[e][f_local][k] (bf16) ----------------
__global__ __launch_bounds__(256) void transW1_kernel(
    const float* __restrict__ W1, unsigned short* __restrict__ W1t, int FC,
    int f0) {
  const int e = blockIdx.z;
  const int fl = blockIdx.x * 64 + (threadIdx.x & 63);
  const int kg = threadIdx.x >> 6;
  const int kbase = (blockIdx.y * 4 + kg) * 32;
  const float* src = W1 + ((size_t)e * 1024 + kbase) * 4096 + f0 + fl;
  unsigned short* dst = W1t + ((size_t)e * FC + fl) * 1024 + kbase;
  for (int i = 0; i < 8; ++i) {
    ushort4 pk;
    pk.x = f2bf(src[(size_t)(i * 4 + 0) * 4096]);
    pk.y = f2bf(src[(size_t)(i * 4 + 1) * 4096]);
    pk.z = f2bf(src[(size_t)(i * 4 + 2) * 4096]);
    pk.w = f2bf(src[(size_t)(i * 4 + 3) * 4096]);
    *(ushort4*)&dst[i * 4] = pk;
  }
}

// ---------------- W2[e][f][d] -> W2t[e][d][f_local] (bf16) ----------------
__global__ __launch_bounds__(256) void transW2_kernel(
    const float* __restrict__ W2, unsigned short* __restrict__ W2t, int FC,
    int f0) {
  const int e = blockIdx.z;
  const int dl = blockIdx.x * 64 + (threadIdx.x & 63);
  const int fg = threadIdx.x >> 6;
  const int fbase = (blockIdx.y * 4 + fg) * 32;
  const float* src = W2 + ((size_t)e * 4096 + f0 + fbase) * 1024 + dl;
  unsigned short* dst = W2t + ((size_t)e * 1024 + dl) * FC + fbase;
  for (int i = 0; i < 8; ++i) {
    ushort4 pk;
    pk.x = f2bf(src[(size_t)(i * 4 + 0) * 1024]);
    pk.y = f2bf(src[(size_t)(i * 4 + 1) * 1024]);
    pk.z = f2bf(src[(size_t)(i * 4 + 2) * 1024]);
    pk.w = f2bf(src[(size_t)(i * 4 + 3) * 1024]);
    *(ushort4*)&dst[i * 4] = pk;
  }
}

// ---------------- GEMM1: H[slot][n] = relu(xb[tok] @ W1t[e] + b1) -----------
// 128x128 tile, BK=32, 4 waves 2x2, gload_lds staging (XOR source-chunk
// swizzle), counted-vmcnt 2-barrier pipeline.
__global__ __launch_bounds__(256) void gemm1_kernel(
    const unsigned short* __restrict__ xb,
    const unsigned short* __restrict__ W1t, const float* __restrict__ b1,
    const int* __restrict__ counts, const int* __restrict__ offsets,
    const int* __restrict__ pair_token, unsigned short* __restrict__ H, int FC,
    int f0, int NT) {
  const int bid = blockIdx.x;
  const int e = bid & 7;  // XCD pinning
  const int lid = bid >> 3;
  const int n0 = (lid % NT) * 128;
  const int m0 = (lid / NT) * 128;
  const int count = counts[e];
  if (m0 >= count) return;
  const int offset = offsets[e];

  __shared__ __align__(16) unsigned short Alds[2][128 * 32];
  __shared__ __align__(16) unsigned short Blds[2][128 * 32];
  __shared__ int toklds[128];

  const int tid = threadIdx.x;
  if (tid < 128) {
    int r = m0 + tid;
    if (r >= count) r = count - 1;
    toklds[tid] = pair_token[offset + r];
  }
  __syncthreads();

  const int lane = tid & 63;
  const int wave = tid >> 6;
  const int srow = lane >> 2;      // row within 16-row group
  const int kc = lane & 3;         // 16B chunk within 32-short window
  const unsigned short* aga[2];
  const unsigned short* bga[2];
  int ldso[2];
#pragma unroll
  for (int i = 0; i < 2; ++i) {
    const int ar = wave * 32 + i * 16 + srow;  // tile-local row
    const int xr = (ar >> 1) & 3;              // source-chunk XOR swizzle
    aga[i] = xb + (size_t)toklds[ar] * 1024 + (kc ^ xr) * 8;
    bga[i] = W1t + ((size_t)e * FC + n0 + ar) * 1024 + (kc ^ xr) * 8;
    ldso[i] = (wave * 32 + i * 16) * 32;
  }

  const int wm = (wave >> 1) * 64;
  const int wn = (wave & 1) * 64;
  const int l16 = lane & 15;
  const int lk = lane >> 4;
  int rdA[4], rdB[4];
#pragma unroll
  for (int mi = 0; mi < 4; ++mi) {
    const int row = wm + mi * 16 + l16;
    rdA[mi] = row * 32 + ((lk ^ ((row >> 1) & 3)) << 3);
  }
#pragma unroll
  for (int nj = 0; nj < 4; ++nj) {
    const int f = wn + nj * 16 + l16;
    rdB[nj] = f * 32 + ((lk ^ ((f >> 1) & 3)) << 3);
  }

  f32x4 acc[4][4] = {};

  auto STAGE = [&](int kt, int buf) {
#pragma unroll
    for (int i = 0; i < 2; ++i) {
      gload_lds16(aga[i] + kt, &Alds[buf][ldso[i]]);
      gload_lds16(bga[i] + kt, &Blds[buf][ldso[i]]);
    }
  };
  auto COMPUTE = [&](int buf) {
    bf16x8 af[4], bfr[4];
#pragma unroll
    for (int mi = 0; mi < 4; ++mi) af[mi] = ldsr128(&Alds[buf][rdA[mi]]);
#pragma unroll
    for (int nj = 0; nj < 4; ++nj) bfr[nj] = ldsr128(&Blds[buf][rdB[nj]]);
    asm volatile("s_waitcnt lgkmcnt(0)" ::: "memory");
    __builtin_amdgcn_sched_barrier(0);
#pragma unroll
    for (int mi = 0; mi < 4; ++mi)
#pragma unroll
      for (int nj = 0; nj < 4; ++nj)
        acc[mi][nj] = __builtin_amdgcn_mfma_f32_16x16x32_bf16(
            af[mi], bfr[nj], acc[mi][nj], 0, 0, 0);
  };

  STAGE(0, 0);  // 4 loads in flight
  for (int t = 0; t < 31; ++t) {
    __builtin_amdgcn_s_barrier();  // A: all waves done reading buf[(t+1)&1]
    STAGE((t + 1) * 32, (t + 1) & 1);
    asm volatile("s_waitcnt vmcnt(4)" ::: "memory");  // own t-loads landed
    __builtin_amdgcn_s_barrier();  // B: buf[t&1] staged by all waves
    __builtin_amdgcn_sched_barrier(0);
    COMPUTE(t & 1);
  }
  asm volatile("s_waitcnt vmcnt(0)" ::: "memory");
  __builtin_amdgcn_s_barrier();
  __builtin_amdgcn_sched_barrier(0);
  COMPUTE(31 & 1);

#pragma unroll
  for (int mi = 0; mi < 4; ++mi) {
#pragma unroll
    for (int r = 0; r < 4; ++r) {
      const int rl = m0 + wm + mi * 16 + lk * 4 + r;
      if (rl >= count) continue;
      unsigned short* hrow = H + (size_t)(offset + rl) * FC;
#pragma unroll
      for (int nj = 0; nj < 4; ++nj) {
        const int c = n0 + wn + nj * 16 + l16;
        float v = acc[mi][nj][r] + b1[e * 4096 + f0 + c];
        hrow[c] = f2bf(v > 0.f ? v : 0.f);
      }
    }
  }
}

// ------- GEMM2: P[slot][d] (+)= H[slot] @ W2t[e] (+ b2) ---------------------
__global__ __launch_bounds__(256) void gemm2_kernel(
    const unsigned short* __restrict__ H,
    const unsigned short* __restrict__ W2t, const float* __restrict__ b2,
    const int* __restrict__ counts, const int* __restrict__ offsets,
    float* __restrict__ P, int FC, int firstChunk) {
  const int bid = blockIdx.x;
  const int e = bid & 7;
  const int lid = bid >> 3;
  const int n0 = (lid & 7) * 128;   // 8 n-tiles (N=1024)
  const int m0 = (lid >> 3) * 128;  // 32 m-tiles
  const int count = counts[e];
  if (m0 >= count) return;
  const int offset = offsets[e];

  __shared__ __align__(16) unsigned short Alds[2][128 * 32];
  __shared__ __align__(16) unsigned short Blds[2][128 * 32];

  const int tid = threadIdx.x;
  const int lane = tid & 63;
  const int wave = tid >> 6;
  const int srow = lane >> 2;
  const int kc = lane & 3;
  const unsigned short* aga[2];
  const unsigned short* bga[2];
  int ldso[2];
#pragma unroll
  for (int i = 0; i < 2; ++i) {
    const int tr = wave * 32 + i * 16 + srow;
    int ar = m0 + tr;
    if (ar >= count) ar = count - 1;
    const int xr = (tr >> 1) & 3;
    aga[i] = H + (size_t)(offset + ar) * FC + (kc ^ xr) * 8;
    bga[i] = W2t + ((size_t)e * 1024 + n0 + tr) * FC + (kc ^ xr) * 8;
    ldso[i] = (wave * 32 + i * 16) * 32;
  }

  const int wm = (wave >> 1) * 64;
  const int wn = (wave & 1) * 64;
  const int l16 = lane & 15;
  const int lk = lane >> 4;
  int rdA[4], rdB[4];
#pragma unroll
  for (int mi = 0; mi < 4; ++mi) {
    const int row = wm + mi * 16 + l16;
    rdA[mi] = row * 32 + ((lk ^ ((row >> 1) & 3)) << 3);
  }
#pragma unroll
  for (int nj = 0; nj < 4; ++nj) {
    const int f = wn + nj * 16 + l16;
    rdB[nj] = f * 32 + ((lk ^ ((f >> 1) & 3)) << 3);
  }

  f32x4 acc[4][4] = {};

  auto STAGE = [&](int kt, int buf) {
#pragma unroll
    for (int i = 0; i < 2; ++i) {
      gload_lds16(aga[i] + kt, &Alds[buf][ldso[i]]);
      gload_lds16(bga[i] + kt, &Blds[buf][ldso[i]]);
    }
  };
  auto COMPUTE = [&](int buf) {
    bf16x8 af[4], bfr[4];
#pragma unroll
    for (int mi = 0; mi < 4; ++mi) af[mi] = ldsr128(&Alds[buf][rdA[mi]]);
#pragma unroll
    for (int nj = 0; nj < 4; ++nj) bfr[nj] = ldsr128(&Blds[buf][rdB[nj]]);
    asm volatile("s_waitcnt lgkmcnt(0)" ::: "memory");
    __builtin_amdgcn_sched_barrier(0);
#pragma unroll
    for (int mi = 0; mi < 4; ++mi)
#pragma unroll
      for (int nj = 0; nj < 4; ++nj)
        acc[mi][nj] = __builtin_amdgcn_mfma_f32_16x16x32_bf16(
            af[mi], bfr[nj], acc[mi][nj], 0, 0, 0);
  };

  const int NTk = FC / 32;
  STAGE(0, 0);
  for (int t = 0; t < NTk - 1; ++t) {
    __builtin_amdgcn_s_barrier();
    STAGE((t + 1) * 32, (t + 1) & 1);
    asm volatile("s_waitcnt vmcnt(4)" ::: "memory");
    __builtin_amdgcn_s_barrier();
    __builtin_amdgcn_sched_barrier(0);
    COMPUTE(t & 1);
  }
  asm volatile("s_waitcnt vmcnt(0)" ::: "memory");
  __builtin_amdgcn_s_barrier();
  __builtin_amdgcn_sched_barrier(0);
  COMPUTE((NTk - 1) & 1);

#pragma unroll
  for (int mi = 0; mi < 4; ++mi) {
#pragma unroll
    for (int r = 0; r < 4; ++r) {
      const int rl = m0 + wm + mi * 16 + lk * 4 + r;
      if (rl >= count) continue;
      float* prow = P + (size_t)(offset + rl) * 1024;
#pragma unroll
      for (int nj = 0; nj < 4; ++nj) {
        const int c = n0 + wn + nj * 16 + l16;
        float v = acc[mi][nj][r];
        if (firstChunk) {
          prow[c] = v + b2[e * 1024 + c];
        } else {
          prow[c] += v;
        }
      }
    }
  }
}

// ---------------- combine: out[t] = w0*P[s0] + w1*P[s1] ----------------
__global__ __launch_bounds__(256) void combine_kernel(
    const float* __restrict__ P, const int* __restrict__ tok_slot,
    const float* __restrict__ tok_w, float* __restrict__ out) {
  const int t = blockIdx.x;
  const int d = threadIdx.x * 4;
  const int s0 = tok_slot[2 * t];
  const int s1 = tok_slot[2 * t + 1];
  const float w0 = tok_w[2 * t];
  const float w1 = tok_w[2 * t + 1];
  const float4 a = *(const float4*)&P[(size_t)s0 * 1024 + d];
  const float4 b = *(const float4*)&P[(size_t)s1 * 1024 + d];
  float4 r;
  r.x = w0 * a.x + w1 * b.x;
  r.y = w0 * a.y + w1 * b.y;
  r.z = w0 * a.z + w1 * b.z;
  r.w = w0 * a.w + w1 * b.w;
  *(float4*)&out[(size_t)t * 1024 + d] = r;
}

extern "C" void kernel_launch(void* const* d_in, const int* in_sizes, int n_in,
                              void* d_out, int out_size, void* d_ws,
                              size_t ws_size, hipStream_t stream) {
  const float* x = (const float*)d_in[0];
  const float* Wg = (const float*)d_in[1];
  const float* bg = (const float*)d_in[2];
  const float* W1 = (const float*)d_in[3];
  const float* b1 = (const float*)d_in[4];
  const float* W2 = (const float*)d_in[5];
  const float* b2 = (const float*)d_in[6];
  float* out = (float*)d_out;

  char* w = (char*)d_ws;
  int* counts = (int*)w;
  int* offsets = counts + 16;
  int* tok_e = (int*)(w + 1024);
  float* tok_w = (float*)(w + 1024 + 32768);
  int* pair_token = (int*)(w + 1024 + 65536);
  int* tok_slot = (int*)(w + 1024 + 98304);
  unsigned short* xb = (unsigned short*)(w + 256 * 1024);  // 8MB
  float* P = (float*)(w + 256 * 1024 + 8 * 1024 * 1024);   // 32MB
  char* big = w + 256 * 1024 + 8 * 1024 * 1024 + 32 * 1024 * 1024;
  const size_t avail =
      ws_size - (256 * 1024 + 8 * 1024 * 1024 + 32 * 1024 * 1024);

  // per-chunk: W1t 16384*FC + W2t 16384*FC + H 16384*FC bytes
  int FC = 4096;
  while (FC > 256 && (size_t)FC * 49152 > avail) FC >>= 1;

  unsigned short* W1t = (unsigned short*)big;
  unsigned short* W2t = W1t + (size_t)8 * FC * 1024;
  unsigned short* Hc = W2t + (size_t)8 * 1024 * FC;

  (void)hipMemsetAsync(counts, 0, 64, stream);

  gate_kernel<<<1024, 256, 0, stream>>>(x, Wg, bg, tok_e, tok_w, counts);
  scan_scatter_kernel<<<1, 256, 0, stream>>>(counts, tok_e, offsets,
                                             pair_token, tok_slot);
  xconv_kernel<<<4096, 256, 0, stream>>>(x, xb);

  const int NT = FC / 128;
  for (int f0 = 0; f0 < 4096; f0 += FC) {
    transW1_kernel<<<dim3(FC / 64, 8, 8), 256, 0, stream>>>(W1, W1t, FC, f0);
    transW2_kernel<<<dim3(16, FC / 128, 8), 256, 0, stream>>>(W2, W2t, FC, f0);
    gemm1_kernel<<<8 * NT * 32, 256, 0, stream>>>(
        xb, W1t, b1, counts, offsets, pair_token, Hc, FC, f0, NT);
    gemm2_kernel<<<8 * 8 * 32, 256, 0, stream>>>(
        Hc, W2t, b2, counts, offsets, P, FC, f0 == 0 ? 1 : 0);
  }
  combine_kernel<<<4096, 256, 0, stream>>>(P, tok_slot, tok_w, out);
}

// Round 9
// 433.289 us; speedup vs baseline: 1.2289x; 1.0919x over previous
//
#include <hip/hip_runtime.h>
#include <hip/hip_bf16.h>

// SimpleMoE: B=2,S=2048 -> 4096 tokens, DIM=1024, FF=4096, E=8, top-2 routing.
// Round 9: (1) 3-buffer depth-2 prefetch pipeline in both GEMMs (vmcnt(8)),
// (2) LDS-tiled coalesced-write weight transposes, (3) xconv fused into gate.
// Keeps round-8 XOR source-chunk swizzle (bank-conflict-free ds_read_b128).

typedef __attribute__((ext_vector_type(8))) short bf16x8;
typedef __attribute__((ext_vector_type(4))) float f32x4;

__device__ __forceinline__ unsigned short f2bf(float f) {
  unsigned u = __builtin_bit_cast(unsigned, f);
  u += 0x7FFFu + ((u >> 16) & 1u);
  return (unsigned short)(u >> 16);
}

__device__ __forceinline__ void gload_lds16(const void* g, void* l) {
  __builtin_amdgcn_global_load_lds(
      (const __attribute__((address_space(1))) unsigned int*)g,
      (__attribute__((address_space(3))) unsigned int*)l, 16, 0, 0);
}

// inline-asm LDS read: keeps the compiler from serializing ds_read behind
// in-flight global_load_lds (false alias) with a vmcnt(0).
__device__ __forceinline__ bf16x8 ldsr128(const void* p) {
  bf16x8 r;
  unsigned a = (unsigned)(unsigned long long)p;
  asm volatile("ds_read_b128 %0, %1" : "=v"(r) : "v"(a));
  return r;
}

// ---------------- gate: logits (fp64), softmax, top-2, counts; also x->bf16 --
__global__ __launch_bounds__(256) void gate_kernel(
    const float* __restrict__ x, const float* __restrict__ Wg,
    const float* __restrict__ bg, int* __restrict__ tok_e,
    float* __restrict__ tok_w, int* __restrict__ counts,
    unsigned short* __restrict__ xb) {
  const int wave = threadIdx.x >> 6;
  const int lane = threadIdx.x & 63;
  const int t = blockIdx.x * 4 + wave;
  const float* xr = x + (size_t)t * 1024;
  unsigned short* xrow = xb + (size_t)t * 1024;
  double acc[8] = {0, 0, 0, 0, 0, 0, 0, 0};
  for (int i = 0; i < 16; ++i) {
    const int d = i * 64 + lane;
    const float vx = xr[d];
    xrow[d] = f2bf(vx);  // fused x -> bf16
    const double xv = (double)vx;
    const float* wr = Wg + d * 8;
#pragma unroll
    for (int e = 0; e < 8; ++e) acc[e] += xv * (double)wr[e];
  }
#pragma unroll
  for (int e = 0; e < 8; ++e) {
    double v = acc[e];
#pragma unroll
    for (int off = 32; off > 0; off >>= 1) v += __shfl_xor(v, off, 64);
    acc[e] = v + (double)bg[e];
  }
  if (lane == 0) {
    int e0 = 0;
#pragma unroll
    for (int e = 1; e < 8; ++e)
      if (acc[e] > acc[e0]) e0 = e;
    int e1 = (e0 == 0) ? 1 : 0;
#pragma unroll
    for (int e = 0; e < 8; ++e) {
      if (e != e0 && acc[e] > acc[e1]) e1 = e;
    }
    const double m = acc[e0];
    double s = 0.0;
#pragma unroll
    for (int e = 0; e < 8; ++e) s += exp(acc[e] - m);
    const double p0 = exp(acc[e0] - m) / s;
    const double p1 = exp(acc[e1] - m) / s;
    const double den = p0 + p1 + 1e-9;
    tok_e[2 * t] = e0;
    tok_e[2 * t + 1] = e1;
    tok_w[2 * t] = (float)(p0 / den);
    tok_w[2 * t + 1] = (float)(p1 / den);
    atomicAdd(&counts[e0], 1);
    atomicAdd(&counts[e1], 1);
  }
}

// ---------------- scan + scatter fused (single block) ----------------
__global__ __launch_bounds__(256) void scan_scatter_kernel(
    const int* __restrict__ counts, const int* __restrict__ tok_e,
    int* __restrict__ offsets, int* __restrict__ pair_token,
    int* __restrict__ tok_slot) {
  __shared__ int scur[8];
  const int tid = threadIdx.x;
  if (tid == 0) {
    int s = 0;
    for (int e = 0; e < 8; ++e) {
      offsets[e] = s;
      scur[e] = s;
      s += counts[e];
    }
  }
  __syncthreads();
  for (int t = tid; t < 4096; t += 256) {
#pragma unroll
    for (int j = 0; j < 2; ++j) {
      const int e = tok_e[2 * t + j];
      const int slot = atomicAdd(&scur[e], 1);
      pair_token[slot] = t;
      tok_slot[2 * t + j] = slot;
    }
  }
}

// -------- W1[e][k][f] -> W1t[e][f-f0][k] (bf16), LDS-tiled 32f x 512k -------
__global__ __launch_bounds__(256) void transW1_kernel(
    const float* __restrict__ W1, unsigned short* __restrict__ W1t, int FC,
    int f0) {
  const int e = blockIdx.z;
  const int fb = blockIdx.x * 32;   // f_local base
  const int kb = blockIdx.y * 512;  // k base
  __shared__ __align__(16) unsigned short T[32][520];  // 520*2=1040B, 16B-mult

  const int tid = threadIdx.x;
  const int fo = tid & 31;   // f within tile (coalesced read dim)
  const int kg = tid >> 5;   // 0..7 -> k-run of 64
  const float* src =
      W1 + ((size_t)e * 1024 + kb + kg * 64) * 4096 + f0 + fb + fo;
#pragma unroll
  for (int i8 = 0; i8 < 8; ++i8) {
    uint4 pk;
    const float* s8 = src + (size_t)i8 * 8 * 4096;
    pk.x = (unsigned)f2bf(s8[0]) | ((unsigned)f2bf(s8[(size_t)4096]) << 16);
    pk.y = (unsigned)f2bf(s8[(size_t)2 * 4096]) |
           ((unsigned)f2bf(s8[(size_t)3 * 4096]) << 16);
    pk.z = (unsigned)f2bf(s8[(size_t)4 * 4096]) |
           ((unsigned)f2bf(s8[(size_t)5 * 4096]) << 16);
    pk.w = (unsigned)f2bf(s8[(size_t)6 * 4096]) |
           ((unsigned)f2bf(s8[(size_t)7 * 4096]) << 16);
    *(uint4*)&T[fo][kg * 64 + i8 * 8] = pk;
  }
  __syncthreads();
  const int fr = tid >> 3;  // 0..31
  const int sg = tid & 7;   // chunk lane
  unsigned short* dst = W1t + ((size_t)e * FC + fb + fr) * 1024 + kb;
#pragma unroll
  for (int j = 0; j < 8; ++j) {
    const int c = sg + j * 8;  // per-instr: sg consecutive -> 128B contiguous
    *(uint4*)(dst + c * 8) = *(const uint4*)&T[fr][c * 8];
  }
}

// -------- W2[e][f][d] -> W2t[e][d][f-f0] (bf16), LDS-tiled 32d x 256f -------
__global__ __launch_bounds__(256) void transW2_kernel(
    const float* __restrict__ W2, unsigned short* __restrict__ W2t, int FC,
    int f0) {
  const int e = blockIdx.z;
  const int db = blockIdx.x * 32;   // d base
  const int fb = blockIdx.y * 256;  // f_local base
  __shared__ __align__(16) unsigned short T[32][264];  // 264*2=528B, 16B-mult

  const int tid = threadIdx.x;
  const int dd = tid & 31;  // d within tile (coalesced read dim)
  const int fg = tid >> 5;  // 0..7 -> f-run of 32
  const float* src =
      W2 + ((size_t)e * 4096 + f0 + fb + fg * 32) * 1024 + db + dd;
#pragma unroll
  for (int i8 = 0; i8 < 4; ++i8) {
    uint4 pk;
    const float* s8 = src + (size_t)i8 * 8 * 1024;
    pk.x = (unsigned)f2bf(s8[0]) | ((unsigned)f2bf(s8[1024]) << 16);
    pk.y = (unsigned)f2bf(s8[2048]) | ((unsigned)f2bf(s8[3072]) << 16);
    pk.z = (unsigned)f2bf(s8[4096]) | ((unsigned)f2bf(s8[5120]) << 16);
    pk.w = (unsigned)f2bf(s8[6144]) | ((unsigned)f2bf(s8[7168]) << 16);
    *(uint4*)&T[dd][fg * 32 + i8 * 8] = pk;
  }
  __syncthreads();
  const int dr = tid >> 3;
  const int sg = tid & 7;
  unsigned short* dst = W2t + ((size_t)e * 1024 + db + dr) * FC + fb;
#pragma unroll
  for (int j = 0; j < 4; ++j) {
    const int c = sg + j * 8;
    *(uint4*)(dst + c * 8) = *(const uint4*)&T[dr][c * 8];
  }
}

// ---------------- GEMM1: H[slot][n] = relu(xb[tok] @ W1t[e] + b1) -----------
// 128x128 tile, BK=32, 4 waves 2x2, gload_lds + XOR swizzle, 3-buf depth-2.
__global__ __launch_bounds__(256) void gemm1_kernel(
    const unsigned short* __restrict__ xb,
    const unsigned short* __restrict__ W1t, const float* __restrict__ b1,
    const int* __restrict__ counts, const int* __restrict__ offsets,
    const int* __restrict__ pair_token, unsigned short* __restrict__ H, int FC,
    int f0, int NT) {
  const int bid = blockIdx.x;
  const int e = bid & 7;  // XCD pinning
  const int lid = bid >> 3;
  const int n0 = (lid % NT) * 128;
  const int m0 = (lid / NT) * 128;
  const int count = counts[e];
  if (m0 >= count) return;
  const int offset = offsets[e];

  __shared__ __align__(16) unsigned short Alds[3][128 * 32];
  __shared__ __align__(16) unsigned short Blds[3][128 * 32];
  __shared__ int toklds[128];

  const int tid = threadIdx.x;
  if (tid < 128) {
    int r = m0 + tid;
    if (r >= count) r = count - 1;
    toklds[tid] = pair_token[offset + r];
  }
  __syncthreads();  // drains everything; vmcnt baseline = 0

  const int lane = tid & 63;
  const int wave = tid >> 6;
  const int srow = lane >> 2;
  const int kc = lane & 3;
  const unsigned short* aga[2];
  const unsigned short* bga[2];
  int ldso[2];
#pragma unroll
  for (int i = 0; i < 2; ++i) {
    const int ar = wave * 32 + i * 16 + srow;
    const int xr = (ar >> 1) & 3;  // source-chunk XOR swizzle
    aga[i] = xb + (size_t)toklds[ar] * 1024 + (kc ^ xr) * 8;
    bga[i] = W1t + ((size_t)e * FC + n0 + ar) * 1024 + (kc ^ xr) * 8;
    ldso[i] = (wave * 32 + i * 16) * 32;
  }

  const int wm = (wave >> 1) * 64;
  const int wn = (wave & 1) * 64;
  const int l16 = lane & 15;
  const int lk = lane >> 4;
  int rdA[4], rdB[4];
#pragma unroll
  for (int mi = 0; mi < 4; ++mi) {
    const int row = wm + mi * 16 + l16;
    rdA[mi] = row * 32 + ((lk ^ ((row >> 1) & 3)) << 3);
  }
#pragma unroll
  for (int nj = 0; nj < 4; ++nj) {
    const int f = wn + nj * 16 + l16;
    rdB[nj] = f * 32 + ((lk ^ ((f >> 1) & 3)) << 3);
  }

  f32x4 acc[4][4] = {};

  auto STAGE = [&](int kt, int buf) {
#pragma unroll
    for (int i = 0; i < 2; ++i) {
      gload_lds16(aga[i] + kt, &Alds[buf][ldso[i]]);
      gload_lds16(bga[i] + kt, &Blds[buf][ldso[i]]);
    }
  };
  auto COMPUTE = [&](int buf) {
    bf16x8 af[4], bfr[4];
#pragma unroll
    for (int mi = 0; mi < 4; ++mi) af[mi] = ldsr128(&Alds[buf][rdA[mi]]);
#pragma unroll
    for (int nj = 0; nj < 4; ++nj) bfr[nj] = ldsr128(&Blds[buf][rdB[nj]]);
    asm volatile("s_waitcnt lgkmcnt(0)" ::: "memory");
    __builtin_amdgcn_sched_barrier(0);
#pragma unroll
    for (int mi = 0; mi < 4; ++mi)
#pragma unroll
      for (int nj = 0; nj < 4; ++nj)
        acc[mi][nj] = __builtin_amdgcn_mfma_f32_16x16x32_bf16(
            af[mi], bfr[nj], acc[mi][nj], 0, 0, 0);
  };

  const int NTk = 32;  // K = 1024
  STAGE(0, 0);
  STAGE(32, 1);  // depth-2: 8 loads in flight
  for (int t = 0; t < NTk; ++t) {
    if (t + 2 < NTk) {
      __builtin_amdgcn_s_barrier();  // buf[(t+2)%3] free (was read at t-1)
      STAGE((t + 2) * 32, (t + 2) % 3);
      asm volatile("s_waitcnt vmcnt(8)" ::: "memory");  // t's loads landed
    } else if (t + 1 < NTk) {
      asm volatile("s_waitcnt vmcnt(4)" ::: "memory");
    } else {
      asm volatile("s_waitcnt vmcnt(0)" ::: "memory");
    }
    __builtin_amdgcn_s_barrier();  // buf[t%3] staged by all waves
    __builtin_amdgcn_sched_barrier(0);
    COMPUTE(t % 3);
  }

#pragma unroll
  for (int mi = 0; mi < 4; ++mi) {
#pragma unroll
    for (int r = 0; r < 4; ++r) {
      const int rl = m0 + wm + mi * 16 + lk * 4 + r;
      if (rl >= count) continue;
      unsigned short* hrow = H + (size_t)(offset + rl) * FC;
#pragma unroll
      for (int nj = 0; nj < 4; ++nj) {
        const int c = n0 + wn + nj * 16 + l16;
        float v = acc[mi][nj][r] + b1[e * 4096 + f0 + c];
        hrow[c] = f2bf(v > 0.f ? v : 0.f);
      }
    }
  }
}

// ------- GEMM2: P[slot][d] (+)= H[slot] @ W2t[e] (+ b2) ---------------------
__global__ __launch_bounds__(256) void gemm2_kernel(
    const unsigned short* __restrict__ H,
    const unsigned short* __restrict__ W2t, const float* __restrict__ b2,
    const int* __restrict__ counts, const int* __restrict__ offsets,
    float* __restrict__ P, int FC, int firstChunk) {
  const int bid = blockIdx.x;
  const int e = bid & 7;
  const int lid = bid >> 3;
  const int n0 = (lid & 7) * 128;   // 8 n-tiles (N=1024)
  const int m0 = (lid >> 3) * 128;  // 32 m-tiles
  const int count = counts[e];
  if (m0 >= count) return;
  const int offset = offsets[e];

  __shared__ __align__(16) unsigned short Alds[3][128 * 32];
  __shared__ __align__(16) unsigned short Blds[3][128 * 32];

  const int tid = threadIdx.x;
  const int lane = tid & 63;
  const int wave = tid >> 6;
  const int srow = lane >> 2;
  const int kc = lane & 3;
  const unsigned short* aga[2];
  const unsigned short* bga[2];
  int ldso[2];
#pragma unroll
  for (int i = 0; i < 2; ++i) {
    const int tr = wave * 32 + i * 16 + srow;
    int ar = m0 + tr;
    if (ar >= count) ar = count - 1;
    const int xr = (tr >> 1) & 3;
    aga[i] = H + (size_t)(offset + ar) * FC + (kc ^ xr) * 8;
    bga[i] = W2t + ((size_t)e * 1024 + n0 + tr) * FC + (kc ^ xr) * 8;
    ldso[i] = (wave * 32 + i * 16) * 32;
  }

  const int wm = (wave >> 1) * 64;
  const int wn = (wave & 1) * 64;
  const int l16 = lane & 15;
  const int lk = lane >> 4;
  int rdA[4], rdB[4];
#pragma unroll
  for (int mi = 0; mi < 4; ++mi) {
    const int row = wm + mi * 16 + l16;
    rdA[mi] = row * 32 + ((lk ^ ((row >> 1) & 3)) << 3);
  }
#pragma unroll
  for (int nj = 0; nj < 4; ++nj) {
    const int f = wn + nj * 16 + l16;
    rdB[nj] = f * 32 + ((lk ^ ((f >> 1) & 3)) << 3);
  }

  f32x4 acc[4][4] = {};

  auto STAGE = [&](int kt, int buf) {
#pragma unroll
    for (int i = 0; i < 2; ++i) {
      gload_lds16(aga[i] + kt, &Alds[buf][ldso[i]]);
      gload_lds16(bga[i] + kt, &Blds[buf][ldso[i]]);
    }
  };
  auto COMPUTE = [&](int buf) {
    bf16x8 af[4], bfr[4];
#pragma unroll
    for (int mi = 0; mi < 4; ++mi) af[mi] = ldsr128(&Alds[buf][rdA[mi]]);
#pragma unroll
    for (int nj = 0; nj < 4; ++nj) bfr[nj] = ldsr128(&Blds[buf][rdB[nj]]);
    asm volatile("s_waitcnt lgkmcnt(0)" ::: "memory");
    __builtin_amdgcn_sched_barrier(0);
#pragma unroll
    for (int mi = 0; mi < 4; ++mi)
#pragma unroll
      for (int nj = 0; nj < 4; ++nj)
        acc[mi][nj] = __builtin_amdgcn_mfma_f32_16x16x32_bf16(
            af[mi], bfr[nj], acc[mi][nj], 0, 0, 0);
  };

  const int NTk = FC / 32;
  STAGE(0, 0);
  STAGE(32, 1);
  for (int t = 0; t < NTk; ++t) {
    if (t + 2 < NTk) {
      __builtin_amdgcn_s_barrier();
      STAGE((t + 2) * 32, (t + 2) % 3);
      asm volatile("s_waitcnt vmcnt(8)" ::: "memory");
    } else if (t + 1 < NTk) {
      asm volatile("s_waitcnt vmcnt(4)" ::: "memory");
    } else {
      asm volatile("s_waitcnt vmcnt(0)" ::: "memory");
    }
    __builtin_amdgcn_s_barrier();
    __builtin_amdgcn_sched_barrier(0);
    COMPUTE(t % 3);
  }

#pragma unroll
  for (int mi = 0; mi < 4; ++mi) {
#pragma unroll
    for (int r = 0; r < 4; ++r) {
      const int rl = m0 + wm + mi * 16 + lk * 4 + r;
      if (rl >= count) continue;
      float* prow = P + (size_t)(offset + rl) * 1024;
#pragma unroll
      for (int nj = 0; nj < 4; ++nj) {
        const int c = n0 + wn + nj * 16 + l16;
        float v = acc[mi][nj][r];
        if (firstChunk) {
          prow[c] = v + b2[e * 1024 + c];
        } else {
          prow[c] += v;
        }
      }
    }
  }
}

// ---------------- combine: out[t] = w0*P[s0] + w1*P[s1] ----------------
__global__ __launch_bounds__(256) void combine_kernel(
    const float* __restrict__ P, const int* __restrict__ tok_slot,
    const float* __restrict__ tok_w, float* __restrict__ out) {
  const int t = blockIdx.x;
  const int d = threadIdx.x * 4;
  const int s0 = tok_slot[2 * t];
  const int s1 = tok_slot[2 * t + 1];
  const float w0 = tok_w[2 * t];
  const float w1 = tok_w[2 * t + 1];
  const float4 a = *(const float4*)&P[(size_t)s0 * 1024 + d];
  const float4 b = *(const float4*)&P[(size_t)s1 * 1024 + d];
  float4 r;
  r.x = w0 * a.x + w1 * b.x;
  r.y = w0 * a.y + w1 * b.y;
  r.z = w0 * a.z + w1 * b.z;
  r.w = w0 * a.w + w1 * b.w;
  *(float4*)&out[(size_t)t * 1024 + d] = r;
}

extern "C" void kernel_launch(void* const* d_in, const int* in_sizes, int n_in,
                              void* d_out, int out_size, void* d_ws,
                              size_t ws_size, hipStream_t stream) {
  const float* x = (const float*)d_in[0];
  const float* Wg = (const float*)d_in[1];
  const float* bg = (const float*)d_in[2];
  const float* W1 = (const float*)d_in[3];
  const float* b1 = (const float*)d_in[4];
  const float* W2 = (const float*)d_in[5];
  const float* b2 = (const float*)d_in[6];
  float* out = (float*)d_out;

  char* w = (char*)d_ws;
  int* counts = (int*)w;
  int* offsets = counts + 16;
  int* tok_e = (int*)(w + 1024);
  float* tok_w = (float*)(w + 1024 + 32768);
  int* pair_token = (int*)(w + 1024 + 65536);
  int* tok_slot = (int*)(w + 1024 + 98304);
  unsigned short* xb = (unsigned short*)(w + 256 * 1024);  // 8MB
  float* P = (float*)(w + 256 * 1024 + 8 * 1024 * 1024);   // 32MB
  char* big = w + 256 * 1024 + 8 * 1024 * 1024 + 32 * 1024 * 1024;
  const size_t avail =
      ws_size - (256 * 1024 + 8 * 1024 * 1024 + 32 * 1024 * 1024);

  // per-chunk: W1t 16384*FC + W2t 16384*FC + H 16384*FC bytes
  int FC = 4096;
  while (FC > 256 && (size_t)FC * 49152 > avail) FC >>= 1;

  unsigned short* W1t = (unsigned short*)big;
  unsigned short* W2t = W1t + (size_t)8 * FC * 1024;
  unsigned short* Hc = W2t + (size_t)8 * 1024 * FC;

  (void)hipMemsetAsync(counts, 0, 64, stream);

  gate_kernel<<<1024, 256, 0, stream>>>(x, Wg, bg, tok_e, tok_w, counts, xb);
  scan_scatter_kernel<<<1, 256, 0, stream>>>(counts, tok_e, offsets,
                                             pair_token, tok_slot);

  const int NT = FC / 128;
  for (int f0 = 0; f0 < 4096; f0 += FC) {
    transW1_kernel<<<dim3(FC / 32, 2, 8), 256, 0, stream>>>(W1, W1t, FC, f0);
    transW2_kernel<<<dim3(32, FC / 256, 8), 256, 0, stream>>>(W2, W2t, FC, f0);
    gemm1_kernel<<<8 * NT * 32, 256, 0, stream>>>(
        xb, W1t, b1, counts, offsets, pair_token, Hc, FC, f0, NT);
    gemm2_kernel<<<8 * 8 * 32, 256, 0, stream>>>(
        Hc, W2t, b2, counts, offsets, P, FC, f0 == 0 ? 1 : 0);
  }
  combine_kernel<<<4096, 256, 0, stream>>>(P, tok_slot, tok_w, out);
}